// Round 5
// baseline (754.414 us; speedup 1.0000x reference)
//
#include <hip/hip_runtime.h>
#include <hip/hip_bf16.h>

#define H_IN 256
#define H    128
#define NL   3
#define BN_EPS 1e-5f
#define NCOPY 32

using u16 = unsigned short;
typedef __attribute__((ext_vector_type(8))) unsigned short us8;

__device__ __forceinline__ float b2f(u16 u) {
    return __uint_as_float(((unsigned int)u) << 16);
}
__device__ __forceinline__ u16 f2b(float f) {  // round-to-nearest-even
    unsigned int u = __float_as_uint(f);
    u += 0x7FFF + ((u >> 16) & 1);
    return (u16)(u >> 16);
}

// ---------------- degree (over row) + dest histogram (over col), one pass ----------------
__global__ void deghist_k(const int* __restrict__ row, const int* __restrict__ col,
                          float* __restrict__ deg, int* __restrict__ cnt, int E) {
    int e = blockIdx.x * blockDim.x + threadIdx.x;
    if (e < E) {
        atomicAdd(&deg[row[e]], 1.0f);
        atomicAdd(&cnt[col[e]], 1);
    }
}

__global__ void dinv_k(const float* __restrict__ deg, float* __restrict__ dinv, int N) {
    int i = blockIdx.x * blockDim.x + threadIdx.x;
    if (i < N) dinv[i] = rsqrtf(deg[i] + 1.0f);  // +1 for self-loop
}

// ---------------- CSR build (sorted by destination col) ----------------
__global__ void scan1_k(const int* __restrict__ cnt, int* __restrict__ rowptr,
                        int* __restrict__ bsum, int N) {
    __shared__ int sh[256];
    int tid = threadIdx.x;
    int i = blockIdx.x * 256 + tid;
    int v = (i < N) ? cnt[i] : 0;
    sh[tid] = v;
    __syncthreads();
    for (int o = 1; o < 256; o <<= 1) {
        int t = (tid >= o) ? sh[tid - o] : 0;
        __syncthreads();
        sh[tid] += t;
        __syncthreads();
    }
    if (i < N) rowptr[i] = sh[tid] - v;
    if (tid == 255) bsum[blockIdx.x] = sh[255];
}

__global__ void scan2_k(int* __restrict__ bsum, int nb) {
    __shared__ int sh[256];
    int tid = threadIdx.x;
    int v = (tid < nb) ? bsum[tid] : 0;
    sh[tid] = v;
    __syncthreads();
    for (int o = 1; o < 256; o <<= 1) {
        int t = (tid >= o) ? sh[tid - o] : 0;
        __syncthreads();
        sh[tid] += t;
        __syncthreads();
    }
    if (tid < nb) bsum[tid] = sh[tid] - v;
}

__global__ void scan3_k(int* __restrict__ rowptr, const int* __restrict__ bsum,
                        int N, int E) {
    int i = blockIdx.x * 256 + threadIdx.x;
    if (i < N) rowptr[i] += bsum[blockIdx.x];
    if (i == 0) rowptr[N] = E;
}

__global__ void scat_k(const int* __restrict__ row, const int* __restrict__ col,
                       const float* __restrict__ dinv, const int* __restrict__ rowptr,
                       int* __restrict__ cursor, int* __restrict__ esrc,
                       float* __restrict__ enorm, int E) {
    int e = blockIdx.x * blockDim.x + threadIdx.x;
    if (e < E) {
        int c = col[e], r = row[e];
        int p = rowptr[c] + atomicAdd(&cursor[c], 1);
        esrc[p]  = r;
        enorm[p] = dinv[r] * dinv[c];
    }
}

// ---------------- layer-0 BN stats: float4 grid-stride, multi-copy atomics ----------------
// stats_mc layout: [NCOPY][2*K]  (sum | sumsq)
__global__ __launch_bounds__(256) void stats0_k(const float* __restrict__ A,
                                                float* __restrict__ stats_mc,
                                                int total4, int K) {
    __shared__ float sh[2 * H_IN];            // max csz = 512
    int tid = threadIdx.x;
    int csz = 2 * K;
    sh[tid] = 0.f;
    sh[tid + 256] = 0.f;
    __syncthreads();
    int gid = blockIdx.x * 256 + tid;
    int stride = gridDim.x * 256;
    int c0 = (gid * 4) % K;                   // fixed: stride*4 % K == 0
    float s0=0.f,s1=0.f,s2=0.f,s3=0.f, q0=0.f,q1=0.f,q2=0.f,q3=0.f;
    const float4* A4 = (const float4*)A;
    for (int i = gid; i < total4; i += stride) {
        float4 v = A4[i];
        s0 += v.x; q0 += v.x * v.x;
        s1 += v.y; q1 += v.y * v.y;
        s2 += v.z; q2 += v.z * v.z;
        s3 += v.w; q3 += v.w * v.w;
    }
    atomicAdd(&sh[c0],     s0); atomicAdd(&sh[K + c0],     q0);
    atomicAdd(&sh[c0 + 1], s1); atomicAdd(&sh[K + c0 + 1], q1);
    atomicAdd(&sh[c0 + 2], s2); atomicAdd(&sh[K + c0 + 2], q2);
    atomicAdd(&sh[c0 + 3], s3); atomicAdd(&sh[K + c0 + 3], q3);
    __syncthreads();
    float* dst = stats_mc + (size_t)(blockIdx.x & (NCOPY - 1)) * csz;
    for (int i = tid; i < csz; i += 256) atomicAdd(&dst[i], sh[i]);
}

// fused: s/t from multi-copy stats inline, W'[k][j]=s[k]W[k][j], b'[j]=bias[j]+sum_k t[k]W[k][j]
__global__ void fold_k(const float* __restrict__ W, const float* __restrict__ stats_mc,
                       const float* __restrict__ g, const float* __restrict__ b,
                       const float* __restrict__ bias, float* __restrict__ Wp,
                       float* __restrict__ bp, int N, int K) {
    int j = blockIdx.x;               // 0..H-1
    int k = threadIdx.x;              // blockDim.x == K
    int csz = 2 * K;
    float sum = 0.f, sumsq = 0.f;
#pragma unroll
    for (int c = 0; c < NCOPY; ++c) {
        sum   += stats_mc[(size_t)c * csz + k];
        sumsq += stats_mc[(size_t)c * csz + K + k];
    }
    float mu = sum / (float)N;
    float var = sumsq / (float)N - mu * mu;
    float s = g[k] * rsqrtf(var + BN_EPS);
    float t = b[k] - mu * s;
    float w = W[(size_t)k * H + j];
    Wp[(size_t)k * H + j] = s * w;
    __shared__ float red[256];
    red[k] = t * w;
    __syncthreads();
    for (int o = blockDim.x >> 1; o > 0; o >>= 1) {
        if (k < o) red[k] += red[k + o];
        __syncthreads();
    }
    if (k == 0) bp[j] = bias[j] + red[0];
}

// ---------------- GEMM: Yb[M x 128] (bf16) = A[M x K] * B[K x 128] ----------------
#define BM 64
#define BK 32
__global__ __launch_bounds__(256) void gemm_k(const float* __restrict__ A,
                                              const float* __restrict__ B,
                                              u16* __restrict__ Yb, int M, int K) {
    __shared__ float Ast[BK][68];
    __shared__ float Bs[BK][H];
    int tid = threadIdx.x;
    int tx = tid & 31;
    int ty = tid >> 5;
    int m0 = blockIdx.x * BM;

    float acc[8][4];
#pragma unroll
    for (int i = 0; i < 8; ++i)
#pragma unroll
        for (int j = 0; j < 4; ++j) acc[i][j] = 0.f;

    int lr = tid >> 2;
    int lk = (tid & 3) * 8;

    for (int kb = 0; kb < K; kb += BK) {
        __syncthreads();
        {
            float av[8];
            int grow = m0 + lr;
            if (grow < M) {
                const float4* p = (const float4*)(A + (size_t)grow * K + kb + lk);
                float4 f0 = p[0], f1 = p[1];
                av[0]=f0.x; av[1]=f0.y; av[2]=f0.z; av[3]=f0.w;
                av[4]=f1.x; av[5]=f1.y; av[6]=f1.z; av[7]=f1.w;
            } else {
#pragma unroll
                for (int j = 0; j < 8; ++j) av[j] = 0.f;
            }
#pragma unroll
            for (int j = 0; j < 8; ++j) Ast[lk + j][lr] = av[j];
        }
        {
            const float4* src = (const float4*)(B + (size_t)kb * H);
            float4* dst = (float4*)&Bs[0][0];
#pragma unroll
            for (int q = 0; q < 4; ++q) {
                int idx = tid + q * 256;
                dst[idx] = src[idx];
            }
        }
        __syncthreads();
#pragma unroll
        for (int k = 0; k < BK; ++k) {
            float4 a0 = *(const float4*)&Ast[k][ty * 8];
            float4 a1 = *(const float4*)&Ast[k][ty * 8 + 4];
            float4 b0 = *(const float4*)&Bs[k][tx * 4];
            float a[8] = {a0.x, a0.y, a0.z, a0.w, a1.x, a1.y, a1.z, a1.w};
            float bb[4] = {b0.x, b0.y, b0.z, b0.w};
#pragma unroll
            for (int i = 0; i < 8; ++i)
#pragma unroll
                for (int j = 0; j < 4; ++j)
                    acc[i][j] = fmaf(a[i], bb[j], acc[i][j]);
        }
    }
#pragma unroll
    for (int i = 0; i < 8; ++i) {
        int grow = m0 + ty * 8 + i;
        if (grow < M) {
            ushort4 v;
            v.x = f2b(acc[i][0]); v.y = f2b(acc[i][1]);
            v.z = f2b(acc[i][2]); v.w = f2b(acc[i][3]);
            *(ushort4*)(Yb + (size_t)grow * H + tx * 4) = v;
        }
    }
}

// ---------------- CSR aggregation (bf16 gather) + fused next-layer BN stats ----------------
// 16 lanes per node (ushort8 = 16B each), 16 nodes per 256-thread block.
// O[i] = dinv[i]^2*Y[i] + bp + sum_p enorm[p]*Y[esrc[p]]
// If do_stats: accumulate per-column sum/sumsq of O into stats_mc (32-copy layout, csz=256).
__global__ __launch_bounds__(256) void csragg_k(const int* __restrict__ rowptr,
                                                const int* __restrict__ esrc,
                                                const float* __restrict__ enorm,
                                                const u16* __restrict__ Yb,
                                                const float* __restrict__ dinv,
                                                const float* __restrict__ bp,
                                                float* __restrict__ O,
                                                float* __restrict__ stats_mc,
                                                int do_stats, int N) {
    __shared__ float sh[2 * H];               // 256 bins: sum | sumsq
    int tid = threadIdx.x;
    sh[tid] = 0.f;
    __syncthreads();

    int node = blockIdx.x * 16 + (tid >> 4);
    int fl = tid & 15;                        // 8-feature group: cols fl*8 .. fl*8+7
    float acc[8];
    if (node < N) {
        const us8* Y8 = (const us8*)Yb;
        {
            us8 ys = Y8[(size_t)node * 16 + fl];
            float d = dinv[node];
            float dd = d * d;
            float4 b0 = ((const float4*)bp)[fl * 2];
            float4 b1 = ((const float4*)bp)[fl * 2 + 1];
            acc[0] = b0.x + dd * b2f(ys[0]); acc[1] = b0.y + dd * b2f(ys[1]);
            acc[2] = b0.z + dd * b2f(ys[2]); acc[3] = b0.w + dd * b2f(ys[3]);
            acc[4] = b1.x + dd * b2f(ys[4]); acc[5] = b1.y + dd * b2f(ys[5]);
            acc[6] = b1.z + dd * b2f(ys[6]); acc[7] = b1.w + dd * b2f(ys[7]);
        }
        int s = rowptr[node], e = rowptr[node + 1];
        int p = s;
        for (; p + 1 < e; p += 2) {
            int s0 = esrc[p], s1 = esrc[p + 1];
            float n0 = enorm[p], n1 = enorm[p + 1];
            us8 v0 = Y8[(size_t)s0 * 16 + fl];
            us8 v1 = Y8[(size_t)s1 * 16 + fl];
#pragma unroll
            for (int j = 0; j < 8; ++j) acc[j] += n0 * b2f(v0[j]);
#pragma unroll
            for (int j = 0; j < 8; ++j) acc[j] += n1 * b2f(v1[j]);
        }
        if (p < e) {
            int s0 = esrc[p];
            float n0 = enorm[p];
            us8 v0 = Y8[(size_t)s0 * 16 + fl];
#pragma unroll
            for (int j = 0; j < 8; ++j) acc[j] += n0 * b2f(v0[j]);
        }
        float4* O4 = (float4*)O;
        O4[(size_t)node * 32 + fl * 2]     = make_float4(acc[0], acc[1], acc[2], acc[3]);
        O4[(size_t)node * 32 + fl * 2 + 1] = make_float4(acc[4], acc[5], acc[6], acc[7]);
        if (do_stats) {
#pragma unroll
            for (int j = 0; j < 8; ++j) {
                atomicAdd(&sh[fl * 8 + j], acc[j]);
                atomicAdd(&sh[H + fl * 8 + j], acc[j] * acc[j]);
            }
        }
    }
    __syncthreads();
    if (do_stats) {
        float* dst = stats_mc + (size_t)(blockIdx.x & (NCOPY - 1)) * (2 * H);
        atomicAdd(&dst[tid], sh[tid]);
    }
}

// ---------------- host ----------------
extern "C" void kernel_launch(void* const* d_in, const int* in_sizes, int n_in,
                              void* d_out, int out_size, void* d_ws, size_t ws_size,
                              hipStream_t stream) {
    const float* x     = (const float*)d_in[0];
    const int*   ei    = (const int*)d_in[1];
    const float* bnfg  = (const float*)d_in[2];
    const float* bnfb  = (const float*)d_in[3];
    const float* Wfeat = (const float*)d_in[4];
    const float* bfeat = (const float*)d_in[5];
    const float* bng   = (const float*)d_in[6];
    const float* bnb   = (const float*)d_in[7];
    const float* Ws    = (const float*)d_in[8];
    const float* bs    = (const float*)d_in[9];

    int N = in_sizes[0] / H_IN;      // 50000
    int E = in_sizes[1] / 2;         // 800000
    const int* row = ei;
    const int* col = ei + E;

    float* w = (float*)d_ws;
    float* deg      = w;  w += N;       // deg (float), reused as cursor later
    int*   cnt      = (int*)w;  w += N;
    float* dinv     = w;  w += N;
    float* stats_mc = w;  w += NCOPY * 2 * H_IN;   // 16384 floats
    float* Wp       = w;  w += H_IN * H;
    float* bp       = w;  w += H;
    int*   rowptr   = (int*)w;  w += N + 4;
    int*   bsum     = (int*)w;  w += 256;
    int*   esrc     = (int*)w;  w += E;
    float* enorm    = w;  w += E;
    u16*   Yb       = (u16*)w;  w += (size_t)N * H / 2;   // bf16 Y
    float* ACT      = w;

    float* out = (float*)d_out;

    // graph prologue: degrees + dest-CSR
    hipMemsetAsync(deg, 0, 2 * N * sizeof(float), stream);   // zero deg + cnt
    deghist_k<<<(E + 255) / 256, 256, 0, stream>>>(row, col, deg, cnt, E);
    dinv_k<<<(N + 255) / 256, 256, 0, stream>>>(deg, dinv, N);
    int nb = (N + 255) / 256;
    scan1_k<<<nb, 256, 0, stream>>>(cnt, rowptr, bsum, N);
    scan2_k<<<1, 256, 0, stream>>>(bsum, nb);
    scan3_k<<<nb, 256, 0, stream>>>(rowptr, bsum, N, E);
    int* cursor = (int*)deg;
    hipMemsetAsync(cursor, 0, N * sizeof(int), stream);
    scat_k<<<(E + 255) / 256, 256, 0, stream>>>(row, col, dinv, rowptr, cursor, esrc, enorm, E);

    // layer-0 BN stats over x (K=256)
    hipMemsetAsync(stats_mc, 0, NCOPY * 2 * H_IN * sizeof(float), stream);
    stats0_k<<<512, 256, 0, stream>>>(x, stats_mc, N * H_IN / 4, H_IN);

    // 4 layers; layer 0 reads x (K=256), layers 1..3 read ACT (K=128).
    for (int l = 0; l < 4; ++l) {
        const float* A    = (l == 0) ? x : ACT;
        int K             = (l == 0) ? H_IN : H;
        const float* W    = (l == 0) ? Wfeat : Ws + (size_t)(l - 1) * H * H;
        const float* bias = (l == 0) ? bfeat : bs + (size_t)(l - 1) * H;
        const float* g    = (l == 0) ? bnfg : bng + (size_t)(l - 1) * H;
        const float* bb   = (l == 0) ? bnfb : bnb + (size_t)(l - 1) * H;
        float* O          = (l == 3) ? out : ACT;
        int do_stats      = (l < 3);

        fold_k<<<H, K, 0, stream>>>(W, stats_mc, g, bb, bias, Wp, bp, N, K);
        gemm_k<<<(N + BM - 1) / BM, 256, 0, stream>>>(A, Wp, Yb, N, K);
        if (do_stats)  // zero stats for next layer before csragg accumulates them
            hipMemsetAsync(stats_mc, 0, NCOPY * 2 * H * sizeof(float), stream);
        csragg_k<<<(N + 15) / 16, 256, 0, stream>>>(rowptr, esrc, enorm, Yb, dinv, bp,
                                                    O, stats_mc, do_stats, N);
    }
}

// Round 6
// 504.593 us; speedup vs baseline: 1.4951x; 1.4951x over previous
//
#include <hip/hip_runtime.h>
#include <hip/hip_bf16.h>

#define H_IN 256
#define H    128
#define BN_EPS 1e-5f
#define NCOPY 32

using u16 = unsigned short;
typedef __attribute__((ext_vector_type(8))) unsigned short us8;
typedef __attribute__((ext_vector_type(8))) short bf16x8;
typedef __attribute__((ext_vector_type(4))) float f32x4;

__device__ __forceinline__ float b2f(u16 u) {
    return __uint_as_float(((unsigned int)u) << 16);
}
__device__ __forceinline__ u16 f2b(float f) {  // round-to-nearest-even
    unsigned int u = __float_as_uint(f);
    u += 0x7FFF + ((u >> 16) & 1);
    return (u16)(u >> 16);
}

// ---------------- degree (over row) + dest histogram (over col), one pass ----------------
__global__ void deghist_k(const int* __restrict__ row, const int* __restrict__ col,
                          float* __restrict__ deg, int* __restrict__ cnt, int E) {
    int e = blockIdx.x * blockDim.x + threadIdx.x;
    if (e < E) {
        atomicAdd(&deg[row[e]], 1.0f);
        atomicAdd(&cnt[col[e]], 1);
    }
}

__global__ void dinv_k(const float* __restrict__ deg, float* __restrict__ dinv, int N) {
    int i = blockIdx.x * blockDim.x + threadIdx.x;
    if (i < N) dinv[i] = rsqrtf(deg[i] + 1.0f);  // +1 for self-loop
}

// ---------------- CSR build (sorted by destination col) ----------------
__global__ void scan1_k(const int* __restrict__ cnt, int* __restrict__ rowptr,
                        int* __restrict__ bsum, int N) {
    __shared__ int sh[256];
    int tid = threadIdx.x;
    int i = blockIdx.x * 256 + tid;
    int v = (i < N) ? cnt[i] : 0;
    sh[tid] = v;
    __syncthreads();
    for (int o = 1; o < 256; o <<= 1) {
        int t = (tid >= o) ? sh[tid - o] : 0;
        __syncthreads();
        sh[tid] += t;
        __syncthreads();
    }
    if (i < N) rowptr[i] = sh[tid] - v;
    if (tid == 255) bsum[blockIdx.x] = sh[255];
}

__global__ void scan2_k(int* __restrict__ bsum, int nb) {
    __shared__ int sh[256];
    int tid = threadIdx.x;
    int v = (tid < nb) ? bsum[tid] : 0;
    sh[tid] = v;
    __syncthreads();
    for (int o = 1; o < 256; o <<= 1) {
        int t = (tid >= o) ? sh[tid - o] : 0;
        __syncthreads();
        sh[tid] += t;
        __syncthreads();
    }
    if (tid < nb) bsum[tid] = sh[tid] - v;
}

__global__ void scan3_k(int* __restrict__ rowptr, const int* __restrict__ bsum,
                        int N, int E) {
    int i = blockIdx.x * 256 + threadIdx.x;
    if (i < N) rowptr[i] += bsum[blockIdx.x];
    if (i == 0) rowptr[N] = E;
}

__global__ void scat_k(const int* __restrict__ row, const int* __restrict__ col,
                       const float* __restrict__ dinv, const int* __restrict__ rowptr,
                       int* __restrict__ cursor, int* __restrict__ esrc,
                       float* __restrict__ enorm, int E) {
    int e = blockIdx.x * blockDim.x + threadIdx.x;
    if (e < E) {
        int c = col[e], r = row[e];
        int p = rowptr[c] + atomicAdd(&cursor[c], 1);
        esrc[p]  = r;
        enorm[p] = dinv[r] * dinv[c];
    }
}

// ---------------- layer-0 BN stats over x + fused x->bf16 conversion ----------------
// stats_mc layout: [NCOPY][2*K]  (sum | sumsq)
__global__ __launch_bounds__(256) void stats0_k(const float* __restrict__ A,
                                                u16* __restrict__ xb,
                                                float* __restrict__ stats_mc,
                                                int total4, int K) {
    __shared__ float sh[2 * H_IN];            // csz = 512
    int tid = threadIdx.x;
    int csz = 2 * K;
    sh[tid] = 0.f;
    sh[tid + 256] = 0.f;
    __syncthreads();
    int gid = blockIdx.x * 256 + tid;
    int stride = gridDim.x * 256;
    int c0 = (gid * 4) % K;                   // fixed: stride*4 % K == 0
    float s0=0.f,s1=0.f,s2=0.f,s3=0.f, q0=0.f,q1=0.f,q2=0.f,q3=0.f;
    const float4* A4 = (const float4*)A;
    ushort4* X4 = (ushort4*)xb;
    for (int i = gid; i < total4; i += stride) {
        float4 v = A4[i];
        ushort4 xv;
        xv.x = f2b(v.x); xv.y = f2b(v.y); xv.z = f2b(v.z); xv.w = f2b(v.w);
        X4[i] = xv;
        s0 += v.x; q0 += v.x * v.x;
        s1 += v.y; q1 += v.y * v.y;
        s2 += v.z; q2 += v.z * v.z;
        s3 += v.w; q3 += v.w * v.w;
    }
    atomicAdd(&sh[c0],     s0); atomicAdd(&sh[K + c0],     q0);
    atomicAdd(&sh[c0 + 1], s1); atomicAdd(&sh[K + c0 + 1], q1);
    atomicAdd(&sh[c0 + 2], s2); atomicAdd(&sh[K + c0 + 2], q2);
    atomicAdd(&sh[c0 + 3], s3); atomicAdd(&sh[K + c0 + 3], q3);
    __syncthreads();
    float* dst = stats_mc + (size_t)(blockIdx.x & (NCOPY - 1)) * csz;
    for (int i = tid; i < csz; i += 256) atomicAdd(&dst[i], sh[i]);
}

// fused fold: s/t from multi-copy stats, W'(bf16)[k][j]=s[k]W[k][j], b'[j]=bias[j]+sum_k t[k]W[k][j]
__global__ void fold_k(const float* __restrict__ W, const float* __restrict__ stats_mc,
                       const float* __restrict__ g, const float* __restrict__ b,
                       const float* __restrict__ bias, u16* __restrict__ Wpb,
                       float* __restrict__ bp, int N, int K) {
    int j = blockIdx.x;               // 0..H-1
    int k = threadIdx.x;              // blockDim.x == K
    int csz = 2 * K;
    float sum = 0.f, sumsq = 0.f;
#pragma unroll
    for (int c = 0; c < NCOPY; ++c) {
        sum   += stats_mc[(size_t)c * csz + k];
        sumsq += stats_mc[(size_t)c * csz + K + k];
    }
    float mu = sum / (float)N;
    float var = sumsq / (float)N - mu * mu;
    float s = g[k] * rsqrtf(var + BN_EPS);
    float t = b[k] - mu * s;
    float w = W[(size_t)k * H + j];
    Wpb[(size_t)k * H + j] = f2b(s * w);
    __shared__ float red[256];
    red[k] = t * w;
    __syncthreads();
    for (int o = blockDim.x >> 1; o > 0; o >>= 1) {
        if (k < o) red[k] += red[k + o];
        __syncthreads();
    }
    if (k == 0) bp[j] = bias[j] + red[0];
}

// ---------------- MFMA GEMM: Yb[M x 128](bf16) = Ab[M x K](bf16) * Bb[K x 128](bf16) ----------------
// Block = 4 waves. Wave w covers cols [32w, 32w+32) as two 16x16x32-MFMA n-tiles.
// B-fragments preloaded per block (persistent across grid-stride M chunks).
// Layouts (verified, learn_hip m89/m91/m120): A[m=lane&15][k=(lane>>4)*8+j],
// B[k=(lane>>4)*8+j][n=lane&15], C/D col=lane&15 row=(lane>>4)*4+reg.
template<int KT>   // KT = K/32
__global__ __launch_bounds__(256) void gemm_mfma_k(const u16* __restrict__ Ab,
                                                   const u16* __restrict__ Bb,
                                                   u16* __restrict__ Yb, int M) {
    const int K = KT * 32;
    int tid = threadIdx.x;
    int w = tid >> 6;
    int lane = tid & 63;
    int m16 = lane & 15;
    int q = lane >> 4;

    bf16x8 bfrag[KT][2];
#pragma unroll
    for (int t = 0; t < KT; ++t)
#pragma unroll
        for (int p = 0; p < 2; ++p) {
            int ncol = 32 * w + 16 * p + m16;
#pragma unroll
            for (int j = 0; j < 8; ++j)
                bfrag[t][p][j] = (short)Bb[(size_t)(32 * t + 8 * q + j) * H + ncol];
        }

    int nchunk = M >> 4;                     // M % 16 == 0
    for (int c = blockIdx.x; c < nchunk; c += gridDim.x) {
        int m0 = c << 4;
        const u16* Arow = Ab + (size_t)(m0 + m16) * K + 8 * q;
        bf16x8 afrag[KT];
#pragma unroll
        for (int t = 0; t < KT; ++t)
            afrag[t] = *(const bf16x8*)(Arow + 32 * t);
        f32x4 acc0 = {0.f, 0.f, 0.f, 0.f}, acc1 = {0.f, 0.f, 0.f, 0.f};
#pragma unroll
        for (int t = 0; t < KT; ++t) {
            acc0 = __builtin_amdgcn_mfma_f32_16x16x32_bf16(afrag[t], bfrag[t][0], acc0, 0, 0, 0);
            acc1 = __builtin_amdgcn_mfma_f32_16x16x32_bf16(afrag[t], bfrag[t][1], acc1, 0, 0, 0);
        }
        u16* Crow = Yb + (size_t)(m0 + q * 4) * H + 32 * w + m16;
#pragma unroll
        for (int i = 0; i < 4; ++i) {
            Crow[(size_t)i * H]      = f2b(acc0[i]);
            Crow[(size_t)i * H + 16] = f2b(acc1[i]);
        }
    }
}

// ---------------- CSR aggregation (bf16 gather) + shuffle-reduced next-layer BN stats ----------------
// 16 lanes per node (us8 = 16B each), 16 nodes per 256-thread block.
// acc = dinv^2*Y[node] + bp + sum_p enorm[p]*Y[esrc[p]]
// Output: Of fp32 (final layer) or Ob bf16 (intermediate). Stats via shfl_xor(16,32) ->
// per-wave LDS partials -> block reduce -> one global atomic per bin.
__global__ __launch_bounds__(256) void csragg_k(const int* __restrict__ rowptr,
                                                const int* __restrict__ esrc,
                                                const float* __restrict__ enorm,
                                                const u16* __restrict__ Yb,
                                                const float* __restrict__ dinv,
                                                const float* __restrict__ bp,
                                                u16* __restrict__ Ob,
                                                float* __restrict__ Of,
                                                float* __restrict__ stats_mc,
                                                int do_stats, int N) {
    __shared__ float sh[1024];                // 4 waves x 256 bins
    int tid = threadIdx.x;
    int node = blockIdx.x * 16 + (tid >> 4);
    int fl = tid & 15;                        // 8-feature group: cols fl*8 .. fl*8+7
    float acc[8] = {0.f, 0.f, 0.f, 0.f, 0.f, 0.f, 0.f, 0.f};
    if (node < N) {
        const us8* Y8 = (const us8*)Yb;
        {
            us8 ys = Y8[(size_t)node * 16 + fl];
            float d = dinv[node];
            float dd = d * d;
            float4 b0 = ((const float4*)bp)[fl * 2];
            float4 b1 = ((const float4*)bp)[fl * 2 + 1];
            acc[0] = b0.x + dd * b2f(ys[0]); acc[1] = b0.y + dd * b2f(ys[1]);
            acc[2] = b0.z + dd * b2f(ys[2]); acc[3] = b0.w + dd * b2f(ys[3]);
            acc[4] = b1.x + dd * b2f(ys[4]); acc[5] = b1.y + dd * b2f(ys[5]);
            acc[6] = b1.z + dd * b2f(ys[6]); acc[7] = b1.w + dd * b2f(ys[7]);
        }
        int s = rowptr[node], e = rowptr[node + 1];
        int p = s;
        for (; p + 1 < e; p += 2) {
            int s0 = esrc[p], s1 = esrc[p + 1];
            float n0 = enorm[p], n1 = enorm[p + 1];
            us8 v0 = Y8[(size_t)s0 * 16 + fl];
            us8 v1 = Y8[(size_t)s1 * 16 + fl];
#pragma unroll
            for (int j = 0; j < 8; ++j) acc[j] += n0 * b2f(v0[j]);
#pragma unroll
            for (int j = 0; j < 8; ++j) acc[j] += n1 * b2f(v1[j]);
        }
        if (p < e) {
            int s0 = esrc[p];
            float n0 = enorm[p];
            us8 v0 = Y8[(size_t)s0 * 16 + fl];
#pragma unroll
            for (int j = 0; j < 8; ++j) acc[j] += n0 * b2f(v0[j]);
        }
        if (Of) {
            float4* O4 = (float4*)Of;
            O4[(size_t)node * 32 + fl * 2]     = make_float4(acc[0], acc[1], acc[2], acc[3]);
            O4[(size_t)node * 32 + fl * 2 + 1] = make_float4(acc[4], acc[5], acc[6], acc[7]);
        } else {
            us8 ov;
#pragma unroll
            for (int j = 0; j < 8; ++j) ov[j] = f2b(acc[j]);
            *(us8*)(Ob + (size_t)node * H + fl * 8) = ov;
        }
    }
    if (do_stats) {
        float sv[16];
#pragma unroll
        for (int j = 0; j < 8; ++j) {
            float a = (node < N) ? acc[j] : 0.f;
            sv[j] = a; sv[8 + j] = a * a;
        }
        // combine the 4 lanes per wave that share fl (lanes fl, fl+16, fl+32, fl+48)
#pragma unroll
        for (int j = 0; j < 16; ++j) {
            sv[j] += __shfl_xor(sv[j], 16, 64);
            sv[j] += __shfl_xor(sv[j], 32, 64);
        }
        int lane = tid & 63, wv = tid >> 6;
        if (lane < 16) {                      // fl == lane here
            float* base = sh + wv * 256;
#pragma unroll
            for (int j = 0; j < 8; ++j) {
                base[fl * 8 + j]       = sv[j];
                base[128 + fl * 8 + j] = sv[8 + j];
            }
        }
        __syncthreads();
        float v = sh[tid] + sh[256 + tid] + sh[512 + tid] + sh[768 + tid];
        atomicAdd(&stats_mc[(size_t)(blockIdx.x & (NCOPY - 1)) * (2 * H) + tid], v);
    }
}

// ---------------- host ----------------
extern "C" void kernel_launch(void* const* d_in, const int* in_sizes, int n_in,
                              void* d_out, int out_size, void* d_ws, size_t ws_size,
                              hipStream_t stream) {
    const float* x     = (const float*)d_in[0];
    const int*   ei    = (const int*)d_in[1];
    const float* bnfg  = (const float*)d_in[2];
    const float* bnfb  = (const float*)d_in[3];
    const float* Wfeat = (const float*)d_in[4];
    const float* bfeat = (const float*)d_in[5];
    const float* bng   = (const float*)d_in[6];
    const float* bnb   = (const float*)d_in[7];
    const float* Ws    = (const float*)d_in[8];
    const float* bs    = (const float*)d_in[9];

    int N = in_sizes[0] / H_IN;      // 50000
    int E = in_sizes[1] / 2;         // 800000
    const int* row = ei;
    const int* col = ei + E;

    float* w = (float*)d_ws;
    float* deg      = w;  w += N;       // reused as cursor later
    int*   cnt      = (int*)w;  w += N;
    float* dinv     = w;  w += N;
    float* stats_mc = w;  w += NCOPY * 2 * H_IN;   // 16384 floats
    u16*   Wpb      = (u16*)w;  w += H_IN * H / 2; // bf16 folded weights
    float* bp       = w;  w += H;
    int*   rowptr   = (int*)w;  w += N + 4;
    int*   bsum     = (int*)w;  w += 256;
    int*   esrc     = (int*)w;  w += E;
    float* enorm    = w;  w += E;
    u16*   xb       = (u16*)w;  w += (size_t)N * H_IN / 2;  // bf16 x
    u16*   Yb       = (u16*)w;  w += (size_t)N * H / 2;     // bf16 gemm out
    u16*   ACTb     = (u16*)w;  w += (size_t)N * H / 2;     // bf16 aggregated act

    float* out = (float*)d_out;

    // graph prologue: degrees + dest-CSR
    hipMemsetAsync(deg, 0, 2 * N * sizeof(float), stream);   // zero deg + cnt
    deghist_k<<<(E + 255) / 256, 256, 0, stream>>>(row, col, deg, cnt, E);
    dinv_k<<<(N + 255) / 256, 256, 0, stream>>>(deg, dinv, N);
    int nb = (N + 255) / 256;
    scan1_k<<<nb, 256, 0, stream>>>(cnt, rowptr, bsum, N);
    scan2_k<<<1, 256, 0, stream>>>(bsum, nb);
    scan3_k<<<nb, 256, 0, stream>>>(rowptr, bsum, N, E);
    int* cursor = (int*)deg;
    hipMemsetAsync(cursor, 0, N * sizeof(int), stream);
    scat_k<<<(E + 255) / 256, 256, 0, stream>>>(row, col, dinv, rowptr, cursor, esrc, enorm, E);

    // layer-0 BN stats over x (K=256) + x -> bf16
    hipMemsetAsync(stats_mc, 0, NCOPY * 2 * H_IN * sizeof(float), stream);
    stats0_k<<<512, 256, 0, stream>>>(x, xb, stats_mc, N * H_IN / 4, H_IN);

    // 4 layers; layer 0 reads xb (K=256), layers 1..3 read ACTb (K=128).
    for (int l = 0; l < 4; ++l) {
        const u16* Ab     = (l == 0) ? xb : ACTb;
        int K             = (l == 0) ? H_IN : H;
        const float* W    = (l == 0) ? Wfeat : Ws + (size_t)(l - 1) * H * H;
        const float* bias = (l == 0) ? bfeat : bs + (size_t)(l - 1) * H;
        const float* g    = (l == 0) ? bnfg : bng + (size_t)(l - 1) * H;
        const float* bb   = (l == 0) ? bnfb : bnb + (size_t)(l - 1) * H;
        int do_stats      = (l < 3);

        fold_k<<<H, K, 0, stream>>>(W, stats_mc, g, bb, bias, Wpb, bp, N, K);
        if (l == 0) gemm_mfma_k<8><<<512, 256, 0, stream>>>(Ab, Wpb, Yb, N);
        else        gemm_mfma_k<4><<<512, 256, 0, stream>>>(Ab, Wpb, Yb, N);
        if (do_stats)  // zero stats for next layer before csragg accumulates them
            hipMemsetAsync(stats_mc, 0, NCOPY * 2 * H * sizeof(float), stream);
        csragg_k<<<(N + 15) / 16, 256, 0, stream>>>(rowptr, esrc, enorm, Yb, dinv, bp,
                                                    ACTb, (l == 3) ? out : nullptr,
                                                    stats_mc, do_stats, N);
    }
}

// Round 7
// 417.475 us; speedup vs baseline: 1.8071x; 1.2087x over previous
//
#include <hip/hip_runtime.h>
#include <hip/hip_bf16.h>

#define H_IN 256
#define H    128
#define BN_EPS 1e-5f
#define NCOPY 32
#define B1   64      // edge slices for radix pipeline
#define SMAX 5120    // sortb LDS staging capacity (max bucket ~4400)

using u16 = unsigned short;
using u32 = unsigned int;
typedef __attribute__((ext_vector_type(8))) unsigned short us8;
typedef __attribute__((ext_vector_type(8))) short bf16x8;
typedef __attribute__((ext_vector_type(4))) float f32x4;

__device__ __forceinline__ float b2f(u16 u) {
    return __uint_as_float(((u32)u) << 16);
}
__device__ __forceinline__ u16 f2b(float f) {  // round-to-nearest-even
    u32 u = __float_as_uint(f);
    u += 0x7FFF + ((u >> 16) & 1);
    return (u16)(u >> 16);
}

// ---------------- radix pass 1: LDS row-histogram halves + coarse col-bucket counts ----------------
// grid = 2*B1 blocks; block b: slice = b>>1, half = b&1.
// dynamic LDS: hist[hwords] (u16-packed pairs for node range [half*halfN, half*halfN+halfN)) + bcnt[256]
__global__ __launch_bounds__(256) void radix1_k(const int* __restrict__ row,
                                                const int* __restrict__ col,
                                                u32* __restrict__ hist_part,
                                                u32* __restrict__ bcnt_part,
                                                int E, int halfN, int hwords) {
    extern __shared__ u32 lds[];
    u32* hist = lds;
    u32* bcnt = lds + hwords;
    int tid = threadIdx.x;
    int slice = blockIdx.x >> 1;
    int half = blockIdx.x & 1;
    for (int i = tid; i < hwords; i += 256) hist[i] = 0;
    if (tid < 256) bcnt[tid] = 0;
    __syncthreads();

    int len = (E + B1 - 1) / B1;
    int e0 = slice * len;
    int e1 = min(e0 + len, E);
    for (int e = e0 + tid; e < e1; e += 256) {
        int r = row[e];
        int h = (r >= halfN) ? 1 : 0;
        if (h == half) {
            int ln = r - half * halfN;
            atomicAdd(&hist[ln >> 1], 1u << ((ln & 1) << 4));
        }
        if (half == 0) atomicAdd(&bcnt[((u32)col[e]) >> 8], 1u);
    }
    __syncthreads();
    u32* hdst = hist_part + (size_t)(slice * 2 + half) * hwords;
    for (int i = tid; i < hwords; i += 256) hdst[i] = hist[i];
    if (half == 0) bcnt_part[slice * 256 + tid] = bcnt[tid];
}

// ---------------- scan bucket counts -> per-(slice,bucket) offsets + bucket bases ----------------
__global__ void scanb_k(const u32* __restrict__ bcnt_part, u32* __restrict__ boff,
                        u32* __restrict__ bbase) {
    __shared__ u32 sh[256];
    int k = threadIdx.x;
    u32 s = 0;
    for (int b = 0; b < B1; ++b) {
        u32 t = bcnt_part[b * 256 + k];
        boff[b * 256 + k] = s;
        s += t;
    }
    u32 own = s;
    sh[k] = s;
    __syncthreads();
    for (int o = 1; o < 256; o <<= 1) {
        u32 t = (k >= o) ? sh[k - o] : 0;
        __syncthreads();
        sh[k] += t;
        __syncthreads();
    }
    u32 base = sh[k] - own;
    bbase[k] = base;
    if (k == 255) bbase[256] = sh[255];  // == E
    for (int b = 0; b < B1; ++b) boff[b * 256 + k] += base;
}

// ---------------- reduce histogram partials -> dinv ----------------
__global__ void dinv2_k(const u32* __restrict__ hist_part, float* __restrict__ dinv,
                        int N, int halfN, int hwords) {
    int w = blockIdx.x * blockDim.x + threadIdx.x;   // word in [0, 2*hwords)
    if (w >= 2 * hwords) return;
    int h = (w >= hwords) ? 1 : 0;
    int lw = w - h * hwords;
    u32 v = 0;
    for (int s = 0; s < B1; ++s) v += hist_part[(size_t)(s * 2 + h) * hwords + lw];
    int n = h * halfN + 2 * lw;
    if (n < N)     dinv[n]     = rsqrtf((float)(v & 0xFFFF) + 1.0f);
    if (n + 1 < N) dinv[n + 1] = rsqrtf((float)(v >> 16) + 1.0f);
}

// ---------------- scatter edges into coarse buckets (LDS cursors) ----------------
// grid = B1 blocks; block = slice. Edge record: row (16b low) | col&255 (bits 16..23)
__global__ __launch_bounds__(256) void scat2_k(const int* __restrict__ row,
                                               const int* __restrict__ col,
                                               const u32* __restrict__ boff,
                                               u32* __restrict__ ebuf, int E) {
    __shared__ u32 cur[256];
    int tid = threadIdx.x;
    int slice = blockIdx.x;
    cur[tid] = boff[slice * 256 + tid];
    __syncthreads();
    int len = (E + B1 - 1) / B1;
    int e0 = slice * len;
    int e1 = min(e0 + len, E);
    for (int e = e0 + tid; e < e1; e += 256) {
        u32 r = (u32)row[e];
        u32 c = (u32)col[e];
        u32 pos = atomicAdd(&cur[c >> 8], 1u);
        ebuf[pos] = r | ((c & 255u) << 16);
    }
}

// ---------------- per-bucket LDS counting sort -> exact CSR (esrc as u16) ----------------
// grid = NB buckets; bucket b covers nodes [256b, 256b+256)
__global__ __launch_bounds__(256) void sortb_k(const u32* __restrict__ ebuf,
                                               const u32* __restrict__ bbase,
                                               int* __restrict__ rowptr,
                                               u16* __restrict__ esrc, int N) {
    __shared__ u32 est[SMAX];
    __shared__ u32 hist[256], scanv[256], cur[256];
    int b = blockIdx.x, tid = threadIdx.x;
    u32 base = bbase[b];
    int size = (int)(bbase[b + 1] - base);
    int st = min(size, SMAX);
    hist[tid] = 0;
    __syncthreads();
    for (int i = tid; i < st; i += 256) {
        u32 e = ebuf[base + i];
        est[i] = e;
        atomicAdd(&hist[(e >> 16) & 255u], 1u);
    }
    for (int i = SMAX + tid; i < size; i += 256) {
        u32 e = ebuf[base + i];
        atomicAdd(&hist[(e >> 16) & 255u], 1u);
    }
    __syncthreads();
    u32 own = hist[tid];
    scanv[tid] = own;
    __syncthreads();
    for (int o = 1; o < 256; o <<= 1) {
        u32 t = (tid >= o) ? scanv[tid - o] : 0;
        __syncthreads();
        scanv[tid] += t;
        __syncthreads();
    }
    u32 excl = scanv[tid] - own;
    int idx = (b << 8) + tid;
    if (idx <= N) rowptr[idx] = (int)(base + excl);
    cur[tid] = excl;
    __syncthreads();
    for (int i = tid; i < st; i += 256) {
        u32 e = est[i];
        u32 pos = atomicAdd(&cur[(e >> 16) & 255u], 1u);
        esrc[base + pos] = (u16)(e & 0xFFFFu);
    }
    for (int i = SMAX + tid; i < size; i += 256) {
        u32 e = ebuf[base + i];
        u32 pos = atomicAdd(&cur[(e >> 16) & 255u], 1u);
        esrc[base + pos] = (u16)(e & 0xFFFFu);
    }
}

// ---------------- layer-0 BN stats over x + fused x->bf16 conversion ----------------
__global__ __launch_bounds__(256) void stats0_k(const float* __restrict__ A,
                                                u16* __restrict__ xb,
                                                float* __restrict__ stats_mc,
                                                int total4, int K) {
    __shared__ float sh[2 * H_IN];
    int tid = threadIdx.x;
    int csz = 2 * K;
    sh[tid] = 0.f;
    sh[tid + 256] = 0.f;
    __syncthreads();
    int gid = blockIdx.x * 256 + tid;
    int stride = gridDim.x * 256;
    int c0 = (gid * 4) % K;
    float s0=0.f,s1=0.f,s2=0.f,s3=0.f, q0=0.f,q1=0.f,q2=0.f,q3=0.f;
    const float4* A4 = (const float4*)A;
    ushort4* X4 = (ushort4*)xb;
    for (int i = gid; i < total4; i += stride) {
        float4 v = A4[i];
        ushort4 xv;
        xv.x = f2b(v.x); xv.y = f2b(v.y); xv.z = f2b(v.z); xv.w = f2b(v.w);
        X4[i] = xv;
        s0 += v.x; q0 += v.x * v.x;
        s1 += v.y; q1 += v.y * v.y;
        s2 += v.z; q2 += v.z * v.z;
        s3 += v.w; q3 += v.w * v.w;
    }
    atomicAdd(&sh[c0],     s0); atomicAdd(&sh[K + c0],     q0);
    atomicAdd(&sh[c0 + 1], s1); atomicAdd(&sh[K + c0 + 1], q1);
    atomicAdd(&sh[c0 + 2], s2); atomicAdd(&sh[K + c0 + 2], q2);
    atomicAdd(&sh[c0 + 3], s3); atomicAdd(&sh[K + c0 + 3], q3);
    __syncthreads();
    float* dst = stats_mc + (size_t)(blockIdx.x & (NCOPY - 1)) * csz;
    for (int i = tid; i < csz; i += 256) atomicAdd(&dst[i], sh[i]);
}

// fold: s/t from multi-copy stats, W'(bf16)=s*W, b' = bias + t@W
__global__ void fold_k(const float* __restrict__ W, const float* __restrict__ stats_mc,
                       const float* __restrict__ g, const float* __restrict__ b,
                       const float* __restrict__ bias, u16* __restrict__ Wpb,
                       float* __restrict__ bp, int N, int K) {
    int j = blockIdx.x;
    int k = threadIdx.x;
    int csz = 2 * K;
    float sum = 0.f, sumsq = 0.f;
#pragma unroll
    for (int c = 0; c < NCOPY; ++c) {
        sum   += stats_mc[(size_t)c * csz + k];
        sumsq += stats_mc[(size_t)c * csz + K + k];
    }
    float mu = sum / (float)N;
    float var = sumsq / (float)N - mu * mu;
    float s = g[k] * rsqrtf(var + BN_EPS);
    float t = b[k] - mu * s;
    float w = W[(size_t)k * H + j];
    Wpb[(size_t)k * H + j] = f2b(s * w);
    __shared__ float red[256];
    red[k] = t * w;
    __syncthreads();
    for (int o = blockDim.x >> 1; o > 0; o >>= 1) {
        if (k < o) red[k] += red[k + o];
        __syncthreads();
    }
    if (k == 0) bp[j] = bias[j] + red[0];
}

// ---------------- MFMA GEMM: Yb = Ab(bf16) * Wpb(bf16), bf16 out ----------------
template<int KT>   // KT = K/32
__global__ __launch_bounds__(256) void gemm_mfma_k(const u16* __restrict__ Ab,
                                                   const u16* __restrict__ Bb,
                                                   u16* __restrict__ Yb, int M) {
    const int K = KT * 32;
    int tid = threadIdx.x;
    int w = tid >> 6;
    int lane = tid & 63;
    int m16 = lane & 15;
    int q = lane >> 4;

    bf16x8 bfrag[KT][2];
#pragma unroll
    for (int t = 0; t < KT; ++t)
#pragma unroll
        for (int p = 0; p < 2; ++p) {
            int ncol = 32 * w + 16 * p + m16;
#pragma unroll
            for (int j = 0; j < 8; ++j)
                bfrag[t][p][j] = (short)Bb[(size_t)(32 * t + 8 * q + j) * H + ncol];
        }

    int nchunk = M >> 4;
    for (int c = blockIdx.x; c < nchunk; c += gridDim.x) {
        int m0 = c << 4;
        const u16* Arow = Ab + (size_t)(m0 + m16) * K + 8 * q;
        bf16x8 afrag[KT];
#pragma unroll
        for (int t = 0; t < KT; ++t)
            afrag[t] = *(const bf16x8*)(Arow + 32 * t);
        f32x4 acc0 = {0.f, 0.f, 0.f, 0.f}, acc1 = {0.f, 0.f, 0.f, 0.f};
#pragma unroll
        for (int t = 0; t < KT; ++t) {
            acc0 = __builtin_amdgcn_mfma_f32_16x16x32_bf16(afrag[t], bfrag[t][0], acc0, 0, 0, 0);
            acc1 = __builtin_amdgcn_mfma_f32_16x16x32_bf16(afrag[t], bfrag[t][1], acc1, 0, 0, 0);
        }
        u16* Crow = Yb + (size_t)(m0 + q * 4) * H + 32 * w + m16;
#pragma unroll
        for (int i = 0; i < 4; ++i) {
            Crow[(size_t)i * H]      = f2b(acc0[i]);
            Crow[(size_t)i * H + 16] = f2b(acc1[i]);
        }
    }
}

// ---------------- CSR aggregation (bf16 gather, u16 esrc, on-the-fly norm) ----------------
// O[i] = bp + dinv[i]*(dinv[i]*Y[i] + sum_p dinv[src]*Y[src])
__global__ __launch_bounds__(256) void csragg_k(const int* __restrict__ rowptr,
                                                const u16* __restrict__ esrc,
                                                const u16* __restrict__ Yb,
                                                const float* __restrict__ dinv,
                                                const float* __restrict__ bp,
                                                u16* __restrict__ Ob,
                                                float* __restrict__ Of,
                                                float* __restrict__ stats_mc,
                                                int do_stats, int N) {
    __shared__ float sh[1024];                // 4 waves x 256 bins
    int tid = threadIdx.x;
    int node = blockIdx.x * 16 + (tid >> 4);
    int fl = tid & 15;
    float o[8] = {0.f,0.f,0.f,0.f,0.f,0.f,0.f,0.f};
    if (node < N) {
        const us8* Y8 = (const us8*)Yb;
        float dn = dinv[node];
        float acc[8];
        {
            us8 ys = Y8[(size_t)node * 16 + fl];
#pragma unroll
            for (int j = 0; j < 8; ++j) acc[j] = dn * b2f(ys[j]);
        }
        int s = rowptr[node], e = rowptr[node + 1];
        int p = s;
        for (; p + 1 < e; p += 2) {
            int s0 = esrc[p], s1 = esrc[p + 1];
            float n0 = dinv[s0], n1 = dinv[s1];
            us8 v0 = Y8[(size_t)s0 * 16 + fl];
            us8 v1 = Y8[(size_t)s1 * 16 + fl];
#pragma unroll
            for (int j = 0; j < 8; ++j) acc[j] += n0 * b2f(v0[j]);
#pragma unroll
            for (int j = 0; j < 8; ++j) acc[j] += n1 * b2f(v1[j]);
        }
        if (p < e) {
            int s0 = esrc[p];
            float n0 = dinv[s0];
            us8 v0 = Y8[(size_t)s0 * 16 + fl];
#pragma unroll
            for (int j = 0; j < 8; ++j) acc[j] += n0 * b2f(v0[j]);
        }
        float4 b0 = ((const float4*)bp)[fl * 2];
        float4 b1 = ((const float4*)bp)[fl * 2 + 1];
        o[0] = b0.x + dn * acc[0]; o[1] = b0.y + dn * acc[1];
        o[2] = b0.z + dn * acc[2]; o[3] = b0.w + dn * acc[3];
        o[4] = b1.x + dn * acc[4]; o[5] = b1.y + dn * acc[5];
        o[6] = b1.z + dn * acc[6]; o[7] = b1.w + dn * acc[7];
        if (Of) {
            float4* O4 = (float4*)Of;
            O4[(size_t)node * 32 + fl * 2]     = make_float4(o[0], o[1], o[2], o[3]);
            O4[(size_t)node * 32 + fl * 2 + 1] = make_float4(o[4], o[5], o[6], o[7]);
        } else {
            us8 ov;
#pragma unroll
            for (int j = 0; j < 8; ++j) ov[j] = f2b(o[j]);
            *(us8*)(Ob + (size_t)node * H + fl * 8) = ov;
        }
    }
    if (do_stats) {
        float sv[16];
#pragma unroll
        for (int j = 0; j < 8; ++j) { sv[j] = o[j]; sv[8 + j] = o[j] * o[j]; }
#pragma unroll
        for (int j = 0; j < 16; ++j) {
            sv[j] += __shfl_xor(sv[j], 16, 64);
            sv[j] += __shfl_xor(sv[j], 32, 64);
        }
        int lane = tid & 63, wv = tid >> 6;
        if (lane < 16) {
            float* base = sh + wv * 256;
#pragma unroll
            for (int j = 0; j < 8; ++j) {
                base[fl * 8 + j]       = sv[j];
                base[128 + fl * 8 + j] = sv[8 + j];
            }
        }
        __syncthreads();
        float v = sh[tid] + sh[256 + tid] + sh[512 + tid] + sh[768 + tid];
        atomicAdd(&stats_mc[(size_t)(blockIdx.x & (NCOPY - 1)) * (2 * H) + tid], v);
    }
}

// ---------------- host ----------------
extern "C" void kernel_launch(void* const* d_in, const int* in_sizes, int n_in,
                              void* d_out, int out_size, void* d_ws, size_t ws_size,
                              hipStream_t stream) {
    const float* x     = (const float*)d_in[0];
    const int*   ei    = (const int*)d_in[1];
    const float* bnfg  = (const float*)d_in[2];
    const float* bnfb  = (const float*)d_in[3];
    const float* Wfeat = (const float*)d_in[4];
    const float* bfeat = (const float*)d_in[5];
    const float* bng   = (const float*)d_in[6];
    const float* bnb   = (const float*)d_in[7];
    const float* Ws    = (const float*)d_in[8];
    const float* bs    = (const float*)d_in[9];

    int N = in_sizes[0] / H_IN;      // 50000  (must be < 65536 for u16 esrc)
    int E = in_sizes[1] / 2;         // 800000
    const int* row = ei;
    const int* col = ei + E;

    int halfN  = (N + 1) / 2;        // 25000
    int hwords = (halfN + 1) / 2;    // 12500
    int NB     = (N + 255) >> 8;     // 196 buckets

    char* p = (char*)d_ws;
    auto alloc = [&](size_t bytes) { char* r = p; p += (bytes + 63) & ~size_t(63); return r; };
    float* dinv      = (float*)alloc(N * 4);
    float* stats_mc  = (float*)alloc(NCOPY * 2 * H_IN * 4);
    u16*   Wpb       = (u16*)alloc(H_IN * H * 2);
    float* bp        = (float*)alloc(H * 4);
    u32*   hist_part = (u32*)alloc((size_t)B1 * 2 * hwords * 4);
    u32*   bcnt_part = (u32*)alloc(B1 * 256 * 4);
    u32*   boff      = (u32*)alloc(B1 * 256 * 4);
    u32*   bbase     = (u32*)alloc(260 * 4);
    int*   rowptr    = (int*)alloc((N + 1) * 4);
    u32*   ebuf      = (u32*)alloc((size_t)E * 4);
    u16*   esrc      = (u16*)alloc((size_t)E * 2);
    u16*   xb        = (u16*)alloc((size_t)N * H_IN * 2);
    u16*   Yb        = (u16*)alloc((size_t)N * H * 2);
    u16*   ACTb      = (u16*)alloc((size_t)N * H * 2);

    float* out = (float*)d_out;

    // graph prologue: LDS-histogram radix CSR build (no random global atomics)
    size_t r1_lds = (size_t)(hwords + 256) * 4;
    radix1_k<<<2 * B1, 256, r1_lds, stream>>>(row, col, hist_part, bcnt_part, E, halfN, hwords);
    scanb_k<<<1, 256, 0, stream>>>(bcnt_part, boff, bbase);
    dinv2_k<<<(2 * hwords + 255) / 256, 256, 0, stream>>>(hist_part, dinv, N, halfN, hwords);
    scat2_k<<<B1, 256, 0, stream>>>(row, col, boff, ebuf, E);
    sortb_k<<<NB, 256, 0, stream>>>(ebuf, bbase, rowptr, esrc, N);

    // layer-0 BN stats over x (K=256) + x -> bf16
    hipMemsetAsync(stats_mc, 0, NCOPY * 2 * H_IN * sizeof(float), stream);
    stats0_k<<<512, 256, 0, stream>>>(x, xb, stats_mc, N * H_IN / 4, H_IN);

    // 4 layers; layer 0 reads xb (K=256), layers 1..3 read ACTb (K=128)
    for (int l = 0; l < 4; ++l) {
        const u16* Ab     = (l == 0) ? xb : ACTb;
        int K             = (l == 0) ? H_IN : H;
        const float* W    = (l == 0) ? Wfeat : Ws + (size_t)(l - 1) * H * H;
        const float* bias = (l == 0) ? bfeat : bs + (size_t)(l - 1) * H;
        const float* g    = (l == 0) ? bnfg : bng + (size_t)(l - 1) * H;
        const float* bb   = (l == 0) ? bnfb : bnb + (size_t)(l - 1) * H;
        int do_stats      = (l < 3);

        fold_k<<<H, K, 0, stream>>>(W, stats_mc, g, bb, bias, Wpb, bp, N, K);
        if (l == 0) gemm_mfma_k<8><<<512, 256, 0, stream>>>(Ab, Wpb, Yb, N);
        else        gemm_mfma_k<4><<<512, 256, 0, stream>>>(Ab, Wpb, Yb, N);
        if (do_stats)
            hipMemsetAsync(stats_mc, 0, NCOPY * 2 * H * sizeof(float), stream);
        csragg_k<<<(N + 15) / 16, 256, 0, stream>>>(rowptr, esrc, Yb, dinv, bp,
                                                    ACTb, (l == 3) ? out : nullptr,
                                                    stats_mc, do_stats, N);
    }
}